// Round 8
// baseline (89.483 us; speedup 1.0000x reference)
//
#include <hip/hip_runtime.h>

#define T_SEQ 4096
#define DMODEL 1024
#define NHEAD 16
#define HDIM 64
#define WIN 128

typedef __attribute__((ext_vector_type(8))) short bf16x8;
typedef __attribute__((ext_vector_type(4))) float f32x4;
typedef __attribute__((ext_vector_type(4))) unsigned short u16x4;

__device__ __forceinline__ unsigned short f2bf(float f) {
  unsigned int u = __builtin_bit_cast(unsigned int, f);
  return (unsigned short)((u + 0x7fffu + ((u >> 16) & 1u)) >> 16);
}

__device__ __forceinline__ void gload_lds16(const unsigned short* g,
                                            unsigned short* l) {
  __builtin_amdgcn_global_load_lds(
      (const __attribute__((address_space(1))) void*)g,
      (__attribute__((address_space(3))) void*)l, 16, 0, 0);
}

// ---------------- fused fp32 -> bf16 converts (one launch) ----------------
__global__ void convert_all(const float* __restrict__ x,
                            const float* __restrict__ w_in,
                            const float* __restrict__ w_out,
                            unsigned short* __restrict__ x_bf,
                            unsigned short* __restrict__ w_in_bf,
                            unsigned short* __restrict__ w_out_bf) {
  int stride = gridDim.x * blockDim.x;
  int t0 = blockIdx.x * blockDim.x + threadIdx.x;
#define CVT(SRC, DST, N4)                                          \
  for (int i = t0; i < (N4); i += stride) {                        \
    float4 v = reinterpret_cast<const float4*>(SRC)[i];            \
    u16x4 o;                                                       \
    o.x = f2bf(v.x); o.y = f2bf(v.y); o.z = f2bf(v.z); o.w = f2bf(v.w); \
    reinterpret_cast<u16x4*>(DST)[i] = o;                          \
  }
  CVT(x, x_bf, T_SEQ * DMODEL / 4)
  CVT(w_in, w_in_bf, 3 * DMODEL * DMODEL / 4)
  CVT(w_out, w_out_bf, DMODEL * DMODEL / 4)
#undef CVT
}

// ---- GEMM, counted double-buffer pipeline: C[t][e] = sum_k A[t][k]*B[e][k]
// 256-row tiles, 8 waves (4x2, wave-tile 64 x BN/2), 1 block/CU (grid 256).
// XCD-ownership block mapping: xcd = idx&7 owns A-panels {2*xcd, 2*xcd+1}
// -> per-XCD A working set 1MB (L2-resident); staged bytes cut ~30%.
// STAGE(t+1) issued before compute(t); raw {vmcnt(0),lgkmcnt(0),s_barrier}
// per K-tile. LDS linear; global source pre-XOR-swizzled; reads XOR back
// (0 bank conflicts, R6-proven).
// EPI 0: qkv epilogue (+b_in, scatter q/k/vt, vt packed x4)
// EPI 1: out epilogue (+b_out, +x residual, fp32 store)
template <int EPI, int BM, int BN>
__global__ __launch_bounds__(512) void gemm_db(
    const unsigned short* __restrict__ A,
    const unsigned short* __restrict__ B,
    const float* __restrict__ bias,
    unsigned short* __restrict__ q_buf,
    unsigned short* __restrict__ k_buf,
    unsigned short* __restrict__ vt_buf,
    const float* __restrict__ x_res,
    float* __restrict__ out) {
  const int K = DMODEL;
  constexpr int NT = DMODEL / 64;           // 16 K-tiles
  constexpr int SM = 64, SN = BN / 2;       // per-wave spans (4x2 wave grid)
  constexpr int MR = SM / 16, NR = SN / 16;
  constexpr int AL = BM / 64, BL = BN / 64; // 16B stage loads per thread
  __shared__ __align__(16) unsigned short As[2 * BM * 64];
  __shared__ __align__(16) unsigned short Bs[2 * BN * 64];

  int tid = threadIdx.x;
  int lane = tid & 63, wave = tid >> 6;     // 8 waves
  int wr = wave >> 1, wc = wave & 1;        // 4 x 2
  int lo = lane & 15, hi = lane >> 4;

  // XCD-ownership mapping (grid = 256 = 16x16 tiles, idx%8 ~ XCD)
  int idx = blockIdx.x;
  int xcd = idx & 7, j = idx >> 3;
  int bx = j & 15;
  int by = xcd * 2 + (j >> 4);
  int t0 = by * BM, e0 = bx * BN;

  f32x4 acc[MR][NR];
#pragma unroll
  for (int m = 0; m < MR; ++m)
#pragma unroll
    for (int n = 0; n < NR; ++n) acc[m][n] = (f32x4){0.f, 0.f, 0.f, 0.f};

  // stage geometry: chunk i = l*512+tid (16B); row = l*64 + (tid>>3);
  // global col8 pre-swizzled: c8 = (tid&7)^((tid>>3)&7); LDS linear at i*16B.
  int c8 = (tid & 7) ^ ((tid >> 3) & 7);
  int srow = tid >> 3;
  const unsigned short* AbaseG = A + (size_t)(t0 + srow) * K + c8 * 8;
  const unsigned short* BbaseG = B + (size_t)(e0 + srow) * K + c8 * 8;
  unsigned short* ldsAu = As + wave * 512;  // + l*4096 + buf*BM*64
  unsigned short* ldsBu = Bs + wave * 512;

  auto stage = [&](int tt) {
    int k0 = tt * 64;
    int ab = (tt & 1) * (BM * 64);
    int bb = (tt & 1) * (BN * 64);
#pragma unroll
    for (int l = 0; l < AL; ++l)
      gload_lds16(AbaseG + (size_t)l * 64 * K + k0, ldsAu + l * 4096 + ab);
#pragma unroll
    for (int l = 0; l < BL; ++l)
      gload_lds16(BbaseG + (size_t)l * 64 * K + k0, ldsBu + l * 4096 + bb);
  };

  stage(0);
  asm volatile("s_waitcnt vmcnt(0) lgkmcnt(0)\n\ts_barrier" ::: "memory");

  for (int t = 0; t < NT; ++t) {
    if (t + 1 < NT) stage(t + 1);  // in flight during compute of tile t
    const unsigned short* Ab = As + (t & 1) * (BM * 64);
    const unsigned short* Bb = Bs + (t & 1) * (BN * 64);
#pragma unroll
    for (int ks = 0; ks < 2; ++ks) {
      bf16x8 af[MR], bfr[NR];
#pragma unroll
      for (int m = 0; m < MR; ++m) {
        int row = wr * SM + m * 16 + lo;
        af[m] = *reinterpret_cast<const bf16x8*>(
            &Ab[row * 64 + (((ks << 2) + hi) ^ (row & 7)) * 8]);
      }
#pragma unroll
      for (int n = 0; n < NR; ++n) {
        int row = wc * SN + n * 16 + lo;
        bfr[n] = *reinterpret_cast<const bf16x8*>(
            &Bb[row * 64 + (((ks << 2) + hi) ^ (row & 7)) * 8]);
      }
#pragma unroll
      for (int m = 0; m < MR; ++m)
#pragma unroll
        for (int n = 0; n < NR; ++n)
          acc[m][n] = __builtin_amdgcn_mfma_f32_16x16x32_bf16(af[m], bfr[n],
                                                              acc[m][n], 0, 0, 0);
    }
    asm volatile("s_waitcnt vmcnt(0) lgkmcnt(0)\n\ts_barrier" ::: "memory");
  }

  int t0w = t0 + wr * SM;
  int e0w = e0 + wc * SN;
#pragma unroll
  for (int m = 0; m < MR; ++m) {
#pragma unroll
    for (int n = 0; n < NR; ++n) {
      int e = e0w + n * 16 + lo;
      float bv = bias[e];
      if (EPI == 0) {
        int part = e >> 10;
        int h = (e >> 6) & 15;
        int d = e & 63;
        if (part == 2) {
          int t = t0w + m * 16 + hi * 4;
          u16x4 pk;
          pk.x = f2bf(acc[m][n][0] + bv);
          pk.y = f2bf(acc[m][n][1] + bv);
          pk.z = f2bf(acc[m][n][2] + bv);
          pk.w = f2bf(acc[m][n][3] + bv);
          *reinterpret_cast<u16x4*>(&vt_buf[((size_t)(h * HDIM + d)) * T_SEQ + t]) = pk;
        } else {
          unsigned short* dst = (part == 0) ? q_buf : k_buf;
#pragma unroll
          for (int jj = 0; jj < 4; ++jj) {
            int t = t0w + m * 16 + hi * 4 + jj;
            dst[((size_t)h * T_SEQ + t) * HDIM + d] = f2bf(acc[m][n][jj] + bv);
          }
        }
      } else {
#pragma unroll
        for (int jj = 0; jj < 4; ++jj) {
          int t = t0w + m * 16 + hi * 4 + jj;
          size_t idxo = (size_t)t * DMODEL + e;
          out[idxo] = acc[m][n][jj] + bv + x_res[idxo];
        }
      }
    }
  }
}

// ---------------- windowed flash attention (no-max softmax, QBLK=32) -------
// 4 waves/block, 1 wave per (head, 32-query tile); 32-key tiles.
// Rotating K-tile register prefetch + hoisted V loads (R6-proven).
__global__ __launch_bounds__(256) void win_attn(
    const unsigned short* __restrict__ q_buf,
    const unsigned short* __restrict__ k_buf,
    const unsigned short* __restrict__ vt_buf,
    unsigned short* __restrict__ ctx) {
  __shared__ __align__(16) unsigned short p_lds[4][2][16 * 40];
  int tid = threadIdx.x;
  int wave = tid >> 6;
  int lane = tid & 63;
  int lo = lane & 15, hi = lane >> 4;

  int id = blockIdx.x;
  int sw = (id & 7) * (512 / 8) + (id >> 3);
  int job = sw * 4 + wave;           // 2048 jobs
  int h = job >> 7;
  int q0 = (job & 127) * 32;
  const float SC = 0.18033688011112042f;  // (1/sqrt(64)) * log2(e)

  bf16x8 aq[2][2];
#pragma unroll
  for (int u = 0; u < 2; ++u) {
    const unsigned short* qrow =
        q_buf + ((size_t)h * T_SEQ + q0 + u * 16 + lo) * HDIM + hi * 8;
    aq[u][0] = *reinterpret_cast<const bf16x8*>(qrow);
    aq[u][1] = *reinterpret_cast<const bf16x8*>(qrow + 32);
  }

  float L[2][4] = {{0.f, 0.f, 0.f, 0.f}, {0.f, 0.f, 0.f, 0.f}};
  f32x4 o[2][4];
#pragma unroll
  for (int u = 0; u < 2; ++u)
#pragma unroll
    for (int n = 0; n < 4; ++n) o[u][n] = (f32x4){0.f, 0.f, 0.f, 0.f};

  int jstart = q0 - WIN; if (jstart < 0) jstart = 0;
  int jend = q0 + 32 + WIN; if (jend > T_SEQ) jend = T_SEQ;

  bf16x8 kc[2][2];
#pragma unroll
  for (int c = 0; c < 2; ++c) {
    const unsigned short* kp =
        k_buf + ((size_t)h * T_SEQ + jstart + c * 16 + lo) * HDIM + hi * 8;
    kc[c][0] = *reinterpret_cast<const bf16x8*>(kp);
    kc[c][1] = *reinterpret_cast<const bf16x8*>(kp + 32);
  }

  for (int j0 = jstart; j0 < jend; j0 += 32) {
    int jn = (j0 + 32 < jend) ? j0 + 32 : jstart;
    bf16x8 kn[2][2];
#pragma unroll
    for (int c = 0; c < 2; ++c) {
      const unsigned short* kp =
          k_buf + ((size_t)h * T_SEQ + jn + c * 16 + lo) * HDIM + hi * 8;
      kn[c][0] = *reinterpret_cast<const bf16x8*>(kp);
      kn[c][1] = *reinterpret_cast<const bf16x8*>(kp + 32);
    }
    bf16x8 bv[4];
#pragma unroll
    for (int n = 0; n < 4; ++n)
      bv[n] = *reinterpret_cast<const bf16x8*>(
          vt_buf + ((size_t)(h * HDIM + n * 16 + lo)) * T_SEQ + j0 + hi * 8);
#pragma unroll
    for (int u = 0; u < 2; ++u) {
#pragma unroll
      for (int c = 0; c < 2; ++c) {
        f32x4 z = (f32x4){0.f, 0.f, 0.f, 0.f};
        z = __builtin_amdgcn_mfma_f32_16x16x32_bf16(aq[u][0], kc[c][0], z, 0, 0, 0);
        z = __builtin_amdgcn_mfma_f32_16x16x32_bf16(aq[u][1], kc[c][1], z, 0, 0, 0);
        int kj = j0 + c * 16 + lo;
#pragma unroll
        for (int jq = 0; jq < 4; ++jq) {
          int q = q0 + u * 16 + hi * 4 + jq;
          bool ok = (q - kj <= WIN) && (kj - q <= WIN);
          float p = ok ? __builtin_amdgcn_exp2f(z[jq] * SC) : 0.f;
          L[u][jq] += p;
          p_lds[wave][u][(hi * 4 + jq) * 40 + c * 16 + lo] = f2bf(p);
        }
      }
    }
    bf16x8 pa[2];
    pa[0] = *reinterpret_cast<const bf16x8*>(&p_lds[wave][0][lo * 40 + hi * 8]);
    pa[1] = *reinterpret_cast<const bf16x8*>(&p_lds[wave][1][lo * 40 + hi * 8]);
#pragma unroll
    for (int n = 0; n < 4; ++n) {
      o[0][n] = __builtin_amdgcn_mfma_f32_16x16x32_bf16(pa[0], bv[n], o[0][n], 0, 0, 0);
      o[1][n] = __builtin_amdgcn_mfma_f32_16x16x32_bf16(pa[1], bv[n], o[1][n], 0, 0, 0);
    }
#pragma unroll
    for (int c = 0; c < 2; ++c) {
      kc[c][0] = kn[c][0];
      kc[c][1] = kn[c][1];
    }
  }
#pragma unroll
  for (int u = 0; u < 2; ++u)
#pragma unroll
    for (int jq = 0; jq < 4; ++jq) {
#pragma unroll
      for (int w = 1; w < 16; w <<= 1) L[u][jq] += __shfl_xor(L[u][jq], w, 64);
    }
#pragma unroll
  for (int u = 0; u < 2; ++u)
#pragma unroll
    for (int jq = 0; jq < 4; ++jq) {
      int t = q0 + u * 16 + hi * 4 + jq;
      float inv = 1.f / L[u][jq];
#pragma unroll
      for (int n = 0; n < 4; ++n)
        ctx[(size_t)t * DMODEL + h * HDIM + n * 16 + lo] = f2bf(o[u][n][jq] * inv);
    }
}

extern "C" void kernel_launch(void* const* d_in, const int* in_sizes, int n_in,
                              void* d_out, int out_size, void* d_ws, size_t ws_size,
                              hipStream_t stream) {
  const float* x = (const float*)d_in[0];
  const float* w_in = (const float*)d_in[1];
  const float* b_in = (const float*)d_in[2];
  const float* w_out = (const float*)d_in[3];
  const float* b_out = (const float*)d_in[4];
  float* out = (float*)d_out;

  char* ws = (char*)d_ws;
  size_t off = 0;
  auto take = [&](size_t bytes) {
    char* p = ws + off;
    off += (bytes + 255) & ~(size_t)255;
    return p;
  };
  unsigned short* x_bf = (unsigned short*)take((size_t)T_SEQ * DMODEL * 2);
  unsigned short* w_in_bf = (unsigned short*)take((size_t)3 * DMODEL * DMODEL * 2);
  unsigned short* w_out_bf = (unsigned short*)take((size_t)DMODEL * DMODEL * 2);
  unsigned short* q_buf = (unsigned short*)take((size_t)T_SEQ * DMODEL * 2);
  unsigned short* k_buf = (unsigned short*)take((size_t)T_SEQ * DMODEL * 2);
  unsigned short* vt_buf = (unsigned short*)take((size_t)T_SEQ * DMODEL * 2 + 8192);
  unsigned short* ctx = (unsigned short*)take((size_t)T_SEQ * DMODEL * 2);

  convert_all<<<2048, 256, 0, stream>>>(x, w_in, w_out, x_bf, w_in_bf, w_out_bf);

  // qkv: M=4096, N=3072, tile 256x192 -> 16x16 = 256 blocks = 1/CU
  gemm_db<0, 256, 192><<<256, 512, 0, stream>>>(x_bf, w_in_bf, b_in, q_buf, k_buf,
                                                vt_buf, nullptr, nullptr);

  win_attn<<<512, 256, 0, stream>>>(q_buf, k_buf, vt_buf, ctx);

  // out-proj: M=4096, N=1024, tile 256x64 -> 16x16 = 256 blocks = 1/CU
  gemm_db<1, 256, 64><<<256, 512, 0, stream>>>(ctx, w_out_bf, b_out, nullptr, nullptr,
                                               nullptr, x, out);
}